// Round 15
// baseline (93.343 us; speedup 1.0000x reference)
//
#include <hip/hip_runtime.h>
#include <math.h>

#define D_ 512
#define H_ 8
#define I_ 64
#define L_ 1024

typedef __attribute__((ext_vector_type(8))) short short8;
typedef __attribute__((ext_vector_type(4))) float f32x4;

__device__ __forceinline__ float sigmoidf_(float x) { return 1.f / (1.f + expf(-x)); }
__device__ __forceinline__ float siluf_(float x) { return x / (1.f + expf(-x)); }

__device__ __forceinline__ unsigned short f2bf(float f) {
    unsigned u = __float_as_uint(f);
    u += 0x7fffu + ((u >> 16) & 1u);   // round-to-nearest-even
    return (unsigned short)(u >> 16);
}
__device__ __forceinline__ float bf2f(unsigned short v) {
    return __uint_as_float((unsigned)v << 16);
}

// Staging tiles are [64 rows][32 k] bf16 with 80B row stride (64B rows alias banks
// every 2 rows -> 8-way b128 conflicts, R8/R9 counters: 2.77M cycles; 80B -> 2-way, free).
#define RS 80        // row stride in bytes
#define RSS 40       // row stride in shorts

struct P {
    const float *x, *w_z, *b_z, *w_za, *b_za, *w_ang, *b_ang, *w_abs, *b_abs;
    const float *w_y, *b_y, *w_ya, *b_ya, *gn_w, *gn_b, *lc_r, *lc_i;
    unsigned short *wtz, *wtza, *wtya, *wty, *gateb, *xb;
    float *a_arr, *r_arr, *Si, *Sr, *zdiag, *Zs_part, *y;
    unsigned *bar;   // 512B zeroed per launch: cnt0@dw0, gen0@dw32, cnt1@dw64, gen1@dw96
};

// software grid barrier: all 768 blocks co-resident (LDS 49.8KB -> 3 blocks/CU,
// __launch_bounds__(256,3) caps VGPR so 3 blocks/CU is guaranteed).
// RELAXED RMW spin (no per-poll L2 invalidate) + one release fence (wbl2) on entry
// and one acquire fence (inv) on exit.  [proven correct + non-poisoning in R9]
__device__ __forceinline__ void gbar(unsigned* cnt, unsigned* gen, unsigned nb) {
    __syncthreads();
    if (threadIdx.x == 0) {
        __builtin_amdgcn_fence(__ATOMIC_RELEASE, "agent");
        unsigned old = __hip_atomic_fetch_add(cnt, 1u, __ATOMIC_RELAXED, __HIP_MEMORY_SCOPE_AGENT);
        if (old == nb - 1u) {
            __hip_atomic_store(gen, 1u, __ATOMIC_RELAXED, __HIP_MEMORY_SCOPE_AGENT);
        } else {
            while (__hip_atomic_fetch_add(gen, 0u, __ATOMIC_RELAXED, __HIP_MEMORY_SCOPE_AGENT) == 0u)
                __builtin_amdgcn_s_sleep(2);
        }
        __builtin_amdgcn_fence(__ATOMIC_ACQUIRE, "agent");
    }
    __syncthreads();
}

union SMemU {
    struct { float sm[64][65]; } a;                                          // 16.6 KB
    struct { short As[2][64 * RSS]; short Bs[2][2][64 * RSS]; float red[64][8];
             float2 buf[2][256]; } b;                                        // 36.9 KB
    struct { unsigned short hA[32][520]; short Bs[2][64 * RSS];
             float Cr[8][65], Ci[8][65], Zd[8][65]; } c;                     // 49.8 KB
};

__global__ __launch_bounds__(256, 3) void mega(P p) {
    __shared__ SMemU smem;
    const int tid = threadIdx.x;
    const int bid = blockIdx.x;
    const unsigned nb = gridDim.x;
    const f32x4 zf = {0.f, 0.f, 0.f, 0.f};

    // ============ PHASE A: W transpose (bids 0-255) | angabs + xb (bids 256-767) ==========
    if (bid < 256) {
        // ---- W[k][n] -> Wt[n][k] bf16 ----
        const int zsel = bid >> 6, tile = bid & 63;
        const float* src = zsel == 0 ? p.w_z : zsel == 1 ? p.w_za : zsel == 2 ? p.w_ya : p.w_y;
        unsigned short* dst = zsel == 0 ? p.wtz : zsel == 1 ? p.wtza : zsel == 2 ? p.wtya : p.wty;
        const int k0 = (tile >> 3) * 64, n0 = (tile & 7) * 64;
#pragma unroll
        for (int i = 0; i < 16; ++i) {
            int idx = tid + i * 256;
            int rr = idx >> 6, cc = idx & 63;
            smem.a.sm[rr][cc] = src[(size_t)(k0 + rr) * 512 + n0 + cc];
        }
        __syncthreads();
#pragma unroll
        for (int i = 0; i < 16; ++i) {
            int idx = tid + i * 256;
            int rr = idx >> 6, cc = idx & 63;   // rr = n-local, cc = k-local
            dst[(size_t)(n0 + rr) * 512 + k0 + cc] = f2bf(smem.a.sm[cc][rr]);
        }
    } else {
        // ---- angabs + xb: stage 4 rows in LDS, emit bf16 x, compute head dots from LDS ----
        float* xs = &smem.a.sm[0][0];          // 2048 floats
        const int t = bid - 256;
        const int n0 = t * 4;
#pragma unroll
        for (int pp = 0; pp < 2; ++pp) {
            int idx = (pp * 256 + tid) * 4;    // 0..2047 floats
            int rr = idx >> 9, cc = idx & 511;
            float4 v = *(const float4*)(p.x + (size_t)(n0 + rr) * 512 + cc);
            *(float4*)(xs + idx) = v;
            ushort4 o = { f2bf(v.x), f2bf(v.y), f2bf(v.z), f2bf(v.w) };
            *(ushort4*)(p.xb + (size_t)(n0 + rr) * 512 + cc) = o;
        }
        __syncthreads();
        const int s = tid & 3, c = (tid >> 2) & 15, r = tid >> 6;
        const int h = c & 7;
        const float* wp = (c < 8) ? p.w_ang : p.w_abs;
        const float* xr = xs + r * 512;
        float acc = 0.f;
#pragma unroll 4
        for (int i = 0; i < 128; ++i) {
            int k = i * 4 + s;
            acc = fmaf(xr[k], wp[k * H_ + h], acc);
        }
        acc += __shfl_xor(acc, 1);
        acc += __shfl_xor(acc, 2);
        if (s == 0) {
            const int n = n0 + r;
            const float scale = expf(-6.9077552789821368f * (h * (1.0f / 7.0f)));  // 0.001^(h/7)
            if (c < 8) { float q = acc + p.b_ang[h]; p.a_arr[(size_t)n * H_ + h] = siluf_(q) * scale; }
            else       { float q = acc + p.b_abs[h]; p.r_arr[(size_t)n * H_ + h] = sigmoidf_(q) * scale; }
        }
    }

    gbar(p.bar + 0, p.bar + 32, nb);

    // ======== PHASE B: scan (0-15) | z/za (16-271) | ya (272-527) | idle (528-767) ========
    if (bid < 16) {
        // ---------- scan: inclusive cumsum over l for one (b,h) ----------
        const int b = bid >> 3, h = bid & 7;
        float2 v[4];
        float2 run = make_float2(0.f, 0.f);
        const size_t base = ((size_t)b * L_ + tid * 4) * H_ + h;
#pragma unroll
        for (int j = 0; j < 4; ++j) {
            run.x += p.a_arr[base + j * H_];
            run.y += p.r_arr[base + j * H_];
            v[j] = run;
        }
        smem.b.buf[0][tid] = run;
        __syncthreads();
        int src = 0;
        for (int off = 1; off < 256; off <<= 1) {
            float2 val = smem.b.buf[src][tid];
            if (tid >= off) { float2 q = smem.b.buf[src][tid - off]; val.x += q.x; val.y += q.y; }
            smem.b.buf[src ^ 1][tid] = val;
            src ^= 1;
            __syncthreads();
        }
        float2 excl = make_float2(0.f, 0.f);
        if (tid > 0) excl = smem.b.buf[src][tid - 1];
#pragma unroll
        for (int j = 0; j < 4; ++j) {
            p.Si[base + j * H_] = v[j].x + excl.x;
            p.Sr[base + j * H_] = -(v[j].y + excl.y);
        }
    } else if (bid < 528) {
        const bool zza = bid < 272;
        const int u = zza ? (bid - 16) : (bid - 272);   // 0..255 (both offsets %8 == 0)
        const int rblk = (u & 7) * 4 + (u >> 6);        // same rblk -> same bid%8 -> same XCD
        const int bx = (u >> 3) & 7;                    // col panel == head
        const int lane = tid & 63, w = tid >> 6;
        const int wm = w >> 1, wn = w & 1;
        const int row0 = rblk * 64, col0 = bx * 64;

        const int sr_ = tid >> 2, sc_ = tid & 3;
        const int sld = sr_ * RS + sc_ * 16;
        const unsigned short* gXa = p.xb + (size_t)(row0 + sr_) * 512 + sc_ * 8;
        const int ck = (lane >> 4) << 4;

        if (zza) {
            const unsigned short* gWz  = p.wtz  + (size_t)(col0 + sr_) * 512 + sc_ * 8;
            const unsigned short* gWza = p.wtza + (size_t)(col0 + sr_) * 512 + sc_ * 8;
            f32x4 accz[2][2], accza[2][2];
#pragma unroll
            for (int a = 0; a < 2; ++a)
#pragma unroll
                for (int bq = 0; bq < 2; ++bq) { accz[a][bq] = zf; accza[a][bq] = zf; }

            int4 rxa, rz, rza;
#define Z_LOAD(K) { rxa = *(const int4*)(gXa + (K)); \
                    rz  = *(const int4*)(gWz  + (K)); rza = *(const int4*)(gWza + (K)); }
#define Z_WRITE(BUF) { *(int4*)((char*)smem.b.As[BUF] + sld) = rxa; \
                       *(int4*)((char*)smem.b.Bs[BUF][0] + sld) = rz; \
                       *(int4*)((char*)smem.b.Bs[BUF][1] + sld) = rza; }
            Z_LOAD(0);
            Z_WRITE(0);
            Z_LOAD(32);
            __syncthreads();
            int cur = 0;
            for (int s = 0; s < 16; ++s) {
                if (s < 15) {
                    Z_WRITE(cur ^ 1);
                    if (s < 14) Z_LOAD((s + 2) * 32);
                }
                short8 af[2], bz[2], bza[2];
#pragma unroll
                for (int fi = 0; fi < 2; ++fi) {
                    int rr = wm * 32 + fi * 16 + (lane & 15);
                    af[fi] = *(const short8*)((const char*)smem.b.As[cur] + rr * RS + ck);
                }
#pragma unroll
                for (int fj = 0; fj < 2; ++fj) {
                    int rr = wn * 32 + fj * 16 + (lane & 15);
                    bz[fj]  = *(const short8*)((const char*)smem.b.Bs[cur][0] + rr * RS + ck);
                    bza[fj] = *(const short8*)((const char*)smem.b.Bs[cur][1] + rr * RS + ck);
                }
#pragma unroll
                for (int fi = 0; fi < 2; ++fi)
#pragma unroll
                    for (int fj = 0; fj < 2; ++fj) {
                        accz[fi][fj]  = __builtin_amdgcn_mfma_f32_16x16x32_bf16(af[fi], bz[fj],  accz[fi][fj],  0, 0, 0);
                        accza[fi][fj] = __builtin_amdgcn_mfma_f32_16x16x32_bf16(af[fi], bza[fj], accza[fi][fj], 0, 0, 0);
                    }
                __syncthreads();
                cur ^= 1;
            }
#undef Z_LOAD
#undef Z_WRITE
            const bool first = (rblk & 15) == 0;
            const int b8 = (rblk >> 4) * 8;
#pragma unroll
            for (int fj = 0; fj < 2; ++fj) {
                float lsum = 0.f;
                int lc = wn * 32 + fj * 16 + (lane & 15);
                int col = col0 + lc;
                float Bz = p.b_z[col], Bza = p.b_za[col];
#pragma unroll
                for (int fi = 0; fi < 2; ++fi) {
#pragma unroll
                    for (int q = 0; q < 4; ++q) {
                        int lr = wm * 32 + fi * 16 + ((lane >> 4) << 2) + q;
                        float pz = accz[fi][fj][q] + Bz;
                        float pza = accza[fi][fj][q] + Bza;
                        float v = pz * siluf_(pza);
                        if (!first || lr > bx) lsum += v;
                        if (first && lr == bx) p.zdiag[(b8 + bx) * 64 + lc] = v;
                    }
                }
                smem.b.red[lc][wm * 4 + (lane >> 4)] = lsum;
            }
            __syncthreads();
            if (tid < 64) {
                float s = 0.f;
#pragma unroll
                for (int j = 0; j < 8; ++j) s += smem.b.red[tid][j];
                p.Zs_part[((size_t)rblk * 8 + bx) * 64 + tid] = s;
            }
        } else {
            const unsigned short* gWya = p.wtya + (size_t)(col0 + sr_) * 512 + sc_ * 8;
            f32x4 accya[2][2];
#pragma unroll
            for (int a = 0; a < 2; ++a)
#pragma unroll
                for (int bq = 0; bq < 2; ++bq) accya[a][bq] = zf;

            int4 rxa, rya;
#define Y_LOAD(K) { rxa = *(const int4*)(gXa + (K)); rya = *(const int4*)(gWya + (K)); }
#define Y_WRITE(BUF) { *(int4*)((char*)smem.b.As[BUF] + sld) = rxa; \
                       *(int4*)((char*)smem.b.Bs[BUF][0] + sld) = rya; }
            Y_LOAD(0);
            Y_WRITE(0);
            Y_LOAD(32);
            __syncthreads();
            int cur = 0;
            for (int s = 0; s < 16; ++s) {
                if (s < 15) {
                    Y_WRITE(cur ^ 1);
                    if (s < 14) Y_LOAD((s + 2) * 32);
                }
                short8 af[2], bya[2];
#pragma unroll
                for (int fi = 0; fi < 2; ++fi) {
                    int rr = wm * 32 + fi * 16 + (lane & 15);
                    af[fi] = *(const short8*)((const char*)smem.b.As[cur] + rr * RS + ck);
                }
#pragma unroll
                for (int fj = 0; fj < 2; ++fj) {
                    int rr = wn * 32 + fj * 16 + (lane & 15);
                    bya[fj] = *(const short8*)((const char*)smem.b.Bs[cur][0] + rr * RS + ck);
                }
#pragma unroll
                for (int fi = 0; fi < 2; ++fi)
#pragma unroll
                    for (int fj = 0; fj < 2; ++fj)
                        accya[fi][fj] = __builtin_amdgcn_mfma_f32_16x16x32_bf16(af[fi], bya[fj], accya[fi][fj], 0, 0, 0);
                __syncthreads();
                cur ^= 1;
            }
#undef Y_LOAD
#undef Y_WRITE
#pragma unroll
            for (int fj = 0; fj < 2; ++fj) {
                int lc = wn * 32 + fj * 16 + (lane & 15);
                int col = col0 + lc;
                float Bya = p.b_ya[col];
#pragma unroll
                for (int fi = 0; fi < 2; ++fi)
#pragma unroll
                    for (int q = 0; q < 4; ++q) {
                        int lr = wm * 32 + fi * 16 + ((lane >> 4) << 2) + q;
                        int row = row0 + lr;
                        p.gateb[(size_t)row * 512 + col] = f2bf(siluf_(accya[fi][fj][q] + Bya));
                    }
            }
        }
    }

    gbar(p.bar + 64, p.bar + 96, nb);

    // ============ PHASE C: hgn + gemm_y, 32-row subtiles (bids 0-511; rest idle) ==========
    if (bid < 512) {
        const int lane = tid & 63, w = tid >> 6;
        const int cbx = bid & 7;
        const int rsub = bid >> 3;                  // 0..63
        const int row0 = rsub * 32, col0 = cbx * 64;
        const int b = row0 >> 10;

        const int brow = tid >> 2, bsc = tid & 3;   // 64 rows x 4 chunks of 16B
        const size_t gB = (size_t)(col0 + brow) * 512 + bsc * 8;
        const int bwr = brow * RS + bsc * 16;
        int4 rw0 = *(const int4*)(p.wty + gB);
        int4 rw1 = *(const int4*)(p.wty + gB + 32);

        for (int uu = tid; uu < 512; uu += 256) {
            int h = uu >> 6, i = uu & 63;
            float s = 0.f;
#pragma unroll
            for (int rb = 0; rb < 16; ++rb)
                s += p.Zs_part[(((size_t)b * 16 + rb) * 8 + h) * 64 + i];
            smem.c.Cr[h][i] = s + p.lc_r[h * 64 + i];
            smem.c.Ci[h][i] = p.lc_i[h * 64 + i];
            smem.c.Zd[h][i] = p.zdiag[((size_t)b * 8 + h) * 64 + i];
        }
        __syncthreads();

        {
            const int r = tid >> 3, h = tid & 7;    // r in 0..31
            const int row = row0 + r;
            const float sr = p.Sr[(size_t)row * 8 + h];
            const float si = p.Si[(size_t)row * 8 + h];
            const float er = expf(sr);
            const float ca = er * cosf(si), sb = er * sinf(si);
            float sum = 0.f, sq = 0.f;
#pragma unroll 8
            for (int i = 0; i < 64; ++i) {
                float hv = smem.c.Zd[h][i] + ca * smem.c.Cr[h][i] - sb * smem.c.Ci[h][i];
                sum += hv; sq += hv * hv;
            }
            const float mean = sum * (1.f / 64.f);
            const float inv = rsqrtf(sq * (1.f / 64.f) - mean * mean + 1e-5f);
            const float gw = p.gn_w[h] * inv;
            const float gb = p.gn_b[h] - mean * gw;
#pragma unroll
            for (int s8 = 0; s8 < 8; ++s8) {
                short8 pk;
#pragma unroll
                for (int j = 0; j < 8; ++j) {
                    int i = s8 * 8 + j;
                    float hv = smem.c.Zd[h][i] + ca * smem.c.Cr[h][i] - sb * smem.c.Ci[h][i];
                    pk[j] = (short)f2bf(hv * gw + gb);
                }
                int slot = (s8 + h) & 7;   // per-head slot rotation: conflict-free writes
                *(short8*)((char*)&smem.c.hA[r][0] + h * 128 + slot * 16) = pk;
            }
        }
        *(int4*)((char*)smem.c.Bs[0] + bwr) = rw0;  // stage Wy tile 0
        __syncthreads();

        f32x4 acc[2] = {zf, zf};
        int cur = 0;
        for (int s = 0; s < 16; ++s) {
            if (s < 15) {
                *(int4*)((char*)smem.c.Bs[cur ^ 1] + bwr) = rw1;
                if (s < 14) rw1 = *(const int4*)(p.wty + gB + (s + 2) * 32);
            }
            const int k0 = s * 32;
            short8 af[2], bf;
            const int hk = k0 >> 6;
            const int t = ((k0 & 32) >> 3) + (lane >> 4);
            const int slot = (t + hk) & 7;          // undo phase-1 rotation
#pragma unroll
            for (int fi = 0; fi < 2; ++fi) {
                int rr = fi * 16 + (lane & 15);
                af[fi] = *(const short8*)((const char*)&smem.c.hA[rr][0] + hk * 128 + slot * 16);
            }
            {
                int rr = w * 16 + (lane & 15);
                bf = *(const short8*)((const char*)smem.c.Bs[cur] + rr * RS + ((lane >> 4) << 4));
            }
            acc[0] = __builtin_amdgcn_mfma_f32_16x16x32_bf16(af[0], bf, acc[0], 0, 0, 0);
            acc[1] = __builtin_amdgcn_mfma_f32_16x16x32_bf16(af[1], bf, acc[1], 0, 0, 0);
            __syncthreads();
            cur ^= 1;
        }

        const int col = col0 + w * 16 + (lane & 15);
        const float By = p.b_y[col];
#pragma unroll
        for (int fi = 0; fi < 2; ++fi)
#pragma unroll
            for (int q = 0; q < 4; ++q) {
                int row = row0 + fi * 16 + ((lane >> 4) << 2) + q;
                size_t idx = (size_t)row * 512 + col;
                p.y[idx] = (acc[fi][q] + By) * bf2f(p.gateb[idx]);
            }
    }
}

extern "C" void kernel_launch(void* const* d_in, const int* in_sizes, int n_in,
                              void* d_out, int out_size, void* d_ws, size_t ws_size,
                              hipStream_t stream) {
    (void)n_in; (void)out_size; (void)ws_size;
    const int BL = in_sizes[0] / D_;   // 2048
    const int B  = BL / L_;            // 2

    unsigned* bar = (unsigned*)d_ws;                              // 512 B barrier state
    unsigned short* wtz  = (unsigned short*)((char*)d_ws + 512);  // 512*512 each
    unsigned short* wtza = wtz  + 512 * 512;
    unsigned short* wtya = wtza + 512 * 512;
    unsigned short* wty  = wtya + 512 * 512;
    unsigned short* gateb= wty  + 512 * 512;                 // BL*512
    unsigned short* xb   = gateb + (size_t)BL * 512;         // BL*512 bf16
    float* a_arr = (float*)(xb + (size_t)BL * 512);          // BL*H
    float* r_arr = a_arr + (size_t)BL * H_;
    float* Si    = r_arr + (size_t)BL * H_;
    float* Sr    = Si    + (size_t)BL * H_;
    float* zdiag = Sr    + (size_t)BL * H_;                  // B*H*I
    float* Zs_part = zdiag + (size_t)B * H_ * I_;            // (BL/64)*H*I

    P hp;
    hp.x     = (const float*)d_in[0];
    hp.w_z   = (const float*)d_in[1];
    hp.b_z   = (const float*)d_in[2];
    hp.w_za  = (const float*)d_in[3];
    hp.b_za  = (const float*)d_in[4];
    hp.w_ang = (const float*)d_in[5];
    hp.b_ang = (const float*)d_in[6];
    hp.w_abs = (const float*)d_in[7];
    hp.b_abs = (const float*)d_in[8];
    hp.w_y   = (const float*)d_in[9];
    hp.b_y   = (const float*)d_in[10];
    hp.w_ya  = (const float*)d_in[11];
    hp.b_ya  = (const float*)d_in[12];
    hp.gn_w  = (const float*)d_in[13];
    hp.gn_b  = (const float*)d_in[14];
    hp.lc_r  = (const float*)d_in[15];
    hp.lc_i  = (const float*)d_in[16];
    hp.wtz = wtz; hp.wtza = wtza; hp.wtya = wtya; hp.wty = wty;
    hp.gateb = gateb; hp.xb = xb;
    hp.a_arr = a_arr; hp.r_arr = r_arr; hp.Si = Si; hp.Sr = Sr;
    hp.zdiag = zdiag; hp.Zs_part = Zs_part;
    hp.y = (float*)d_out;
    hp.bar = bar;

    const int grid = 256 + BL / 4;   // 768: phase-A coverage; >= all phase-B/C needs
    (void)hipMemsetAsync(bar, 0, 512, stream);
    mega<<<grid, 256, 0, stream>>>(hp);
}

// Round 16
// 40.396 us; speedup vs baseline: 2.3107x; 2.3107x over previous
//
#include <hip/hip_runtime.h>
#include <math.h>

#define D_ 512
#define H_ 8
#define I_ 64
#define L_ 1024

typedef __attribute__((ext_vector_type(8))) short short8;
typedef __attribute__((ext_vector_type(4))) float f32x4;

__device__ __forceinline__ float sigmoidf_(float x) { return 1.f / (1.f + expf(-x)); }
__device__ __forceinline__ float siluf_(float x) { return x / (1.f + expf(-x)); }

__device__ __forceinline__ unsigned short f2bf(float f) {
    unsigned u = __float_as_uint(f);
    u += 0x7fffu + ((u >> 16) & 1u);   // round-to-nearest-even
    return (unsigned short)(u >> 16);
}
__device__ __forceinline__ float bf2f(unsigned short v) {
    return __uint_as_float((unsigned)v << 16);
}

// Staging tiles are [64 rows][32 k] bf16 with 80B row stride (64B rows alias banks
// every 2 rows -> 8-way b128 conflicts, R8/R9: 2.77M cycles; 80B -> 2-way, free).
#define RS 80        // row stride in bytes
#define RSS 40       // row stride in shorts

// ========== K1: 4x W transpose (256 blocks) + angabs heads + xb bf16 (BL/4 blocks) ==========
__global__ __launch_bounds__(256) void k1_prep(
    const float* __restrict__ x, unsigned short* __restrict__ xb,
    const float* __restrict__ w0, const float* __restrict__ w1,
    const float* __restrict__ w2, const float* __restrict__ w3,
    unsigned short* __restrict__ t0, unsigned short* __restrict__ t1,
    unsigned short* __restrict__ t2, unsigned short* __restrict__ t3,
    const float* __restrict__ w_ang, const float* __restrict__ b_ang,
    const float* __restrict__ w_abs, const float* __restrict__ b_abs,
    float* __restrict__ a_out, float* __restrict__ r_out)
{
    __shared__ float sm[64][65];
    const int tid = threadIdx.x;
    const int bid = blockIdx.x;
    if (bid < 256) {
        // ---- W[k][n] -> Wt[n][k] bf16 ----
        int zsel = bid >> 6, tile = bid & 63;
        const float* src = zsel == 0 ? w0 : zsel == 1 ? w1 : zsel == 2 ? w2 : w3;
        unsigned short* dst = zsel == 0 ? t0 : zsel == 1 ? t1 : zsel == 2 ? t2 : t3;
        const int k0 = (tile >> 3) * 64, n0 = (tile & 7) * 64;
#pragma unroll
        for (int i = 0; i < 16; ++i) {
            int idx = tid + i * 256;
            int rr = idx >> 6, cc = idx & 63;
            sm[rr][cc] = src[(size_t)(k0 + rr) * 512 + n0 + cc];
        }
        __syncthreads();
#pragma unroll
        for (int i = 0; i < 16; ++i) {
            int idx = tid + i * 256;
            int rr = idx >> 6, cc = idx & 63;   // rr = n-local, cc = k-local
            dst[(size_t)(n0 + rr) * 512 + k0 + cc] = f2bf(sm[cc][rr]);
        }
        return;
    }
    // ---- angabs + xb: stage 4 rows in LDS, emit bf16 x, compute head dots from LDS ----
    {
        float* xs = &sm[0][0];                 // 2048 floats (fits in sm)
        const int t = bid - 256;
        const int n0 = t * 4;
#pragma unroll
        for (int p = 0; p < 2; ++p) {
            int idx = (p * 256 + tid) * 4;     // 0..2047 floats
            int rr = idx >> 9, cc = idx & 511;
            float4 v = *(const float4*)(x + (size_t)(n0 + rr) * 512 + cc);
            *(float4*)(xs + idx) = v;
            ushort4 o = { f2bf(v.x), f2bf(v.y), f2bf(v.z), f2bf(v.w) };
            *(ushort4*)(xb + (size_t)(n0 + rr) * 512 + cc) = o;
        }
        __syncthreads();
        const int s = tid & 3, c = (tid >> 2) & 15, r = tid >> 6;
        const int h = c & 7;
        const float* wp = (c < 8) ? w_ang : w_abs;
        const float* xr = xs + r * 512;
        float acc = 0.f;
#pragma unroll 4
        for (int i = 0; i < 128; ++i) {
            int k = i * 4 + s;
            acc = fmaf(xr[k], wp[k * H_ + h], acc);
        }
        acc += __shfl_xor(acc, 1);
        acc += __shfl_xor(acc, 2);
        if (s == 0) {
            const int n = n0 + r;
            const float scale = expf(-6.9077552789821368f * (h * (1.0f / 7.0f)));  // 0.001^(h/7)
            if (c < 8) { float p = acc + b_ang[h]; a_out[(size_t)n * H_ + h] = siluf_(p) * scale; }
            else       { float p = acc + b_abs[h]; r_out[(size_t)n * H_ + h] = sigmoidf_(p) * scale; }
        }
    }
}

// ===== K2: split GEMM families (2 blocks/CU), A = pre-converted bf16 (pure int4 staging) =====
// grid = 16 + 256 + 256:
//   bids [0,16):    scan riders; [16,272): z/za -> Zs_part,zdiag; [272,528): ya -> gateb
// XCD remap: same-rblk blocks share bid%8 -> x panel read once per XCD.
__global__ __launch_bounds__(256) void k2_split(
    const unsigned short* __restrict__ xb,
    const unsigned short* __restrict__ Wz, const unsigned short* __restrict__ Wza,
    const unsigned short* __restrict__ Wya,
    const float* __restrict__ b_z, const float* __restrict__ b_za, const float* __restrict__ b_ya,
    unsigned short* __restrict__ gateb, float* __restrict__ Zs_part, float* __restrict__ zdiag,
    const float* __restrict__ a_arr, const float* __restrict__ r_arr,
    float* __restrict__ Si, float* __restrict__ Sr)
{
    __shared__ short As[2][64 * RSS];
    __shared__ short Bs[2][2][64 * RSS];
    __shared__ float red[64][8];
    __shared__ float2 buf[2][256];
    const int tid = threadIdx.x;
    const int bid = blockIdx.x;

    if (bid < 16) {
        // ---------- scan rider: inclusive cumsum over l for one (b,h) ----------
        const int b = bid >> 3, h = bid & 7;
        float2 v[4];
        float2 run = make_float2(0.f, 0.f);
        const size_t base = ((size_t)b * L_ + tid * 4) * H_ + h;
#pragma unroll
        for (int j = 0; j < 4; ++j) {
            run.x += a_arr[base + j * H_];
            run.y += r_arr[base + j * H_];
            v[j] = run;
        }
        buf[0][tid] = run;
        __syncthreads();
        int src = 0;
        for (int off = 1; off < 256; off <<= 1) {
            float2 val = buf[src][tid];
            if (tid >= off) { float2 q = buf[src][tid - off]; val.x += q.x; val.y += q.y; }
            buf[src ^ 1][tid] = val;
            src ^= 1;
            __syncthreads();
        }
        float2 excl = make_float2(0.f, 0.f);
        if (tid > 0) excl = buf[src][tid - 1];
#pragma unroll
        for (int j = 0; j < 4; ++j) {
            Si[base + j * H_] = v[j].x + excl.x;
            Sr[base + j * H_] = -(v[j].y + excl.y);
        }
        return;
    }

    const bool zza = bid < 272;
    const int u = zza ? (bid - 16) : (bid - 272);   // 0..255 (both offsets %8 == 0)
    const int rblk = (u & 7) * 4 + (u >> 6);        // same rblk -> same bid%8 -> same XCD
    const int bx = (u >> 3) & 7;                    // col panel == head
    const int lane = tid & 63, w = tid >> 6;
    const int wm = w >> 1, wn = w & 1;
    const int row0 = rblk * 64, col0 = bx * 64;

    const f32x4 zf = {0.f, 0.f, 0.f, 0.f};
    const int sr_ = tid >> 2, sc_ = tid & 3;
    const int sld = sr_ * RS + sc_ * 16;            // padded-stride LDS byte offset
    const unsigned short* gXa = xb + (size_t)(row0 + sr_) * 512 + sc_ * 8;
    const int ck = (lane >> 4) << 4;                // 16B chunk within row

    if (zza) {
        // ================= z/za family =================
        const unsigned short* gWz  = Wz  + (size_t)(col0 + sr_) * 512 + sc_ * 8;
        const unsigned short* gWza = Wza + (size_t)(col0 + sr_) * 512 + sc_ * 8;
        f32x4 accz[2][2], accza[2][2];
#pragma unroll
        for (int a = 0; a < 2; ++a)
#pragma unroll
            for (int bq = 0; bq < 2; ++bq) { accz[a][bq] = zf; accza[a][bq] = zf; }

        int4 rxa, rz, rza;
#define Z_LOAD(K) { rxa = *(const int4*)(gXa + (K)); \
                    rz  = *(const int4*)(gWz  + (K)); rza = *(const int4*)(gWza + (K)); }
#define Z_WRITE(BUF) { *(int4*)((char*)As[BUF] + sld) = rxa; \
                       *(int4*)((char*)Bs[BUF][0] + sld) = rz; \
                       *(int4*)((char*)Bs[BUF][1] + sld) = rza; }

        Z_LOAD(0);
        Z_WRITE(0);
        Z_LOAD(32);
        __syncthreads();

        int cur = 0;
        for (int s = 0; s < 16; ++s) {
            if (s < 15) {
                Z_WRITE(cur ^ 1);
                if (s < 14) Z_LOAD((s + 2) * 32);
            }
            short8 af[2], bz[2], bza[2];
#pragma unroll
            for (int fi = 0; fi < 2; ++fi) {
                int rr = wm * 32 + fi * 16 + (lane & 15);
                af[fi] = *(const short8*)((const char*)As[cur] + rr * RS + ck);
            }
#pragma unroll
            for (int fj = 0; fj < 2; ++fj) {
                int rr = wn * 32 + fj * 16 + (lane & 15);
                bz[fj]  = *(const short8*)((const char*)Bs[cur][0] + rr * RS + ck);
                bza[fj] = *(const short8*)((const char*)Bs[cur][1] + rr * RS + ck);
            }
#pragma unroll
            for (int fi = 0; fi < 2; ++fi)
#pragma unroll
                for (int fj = 0; fj < 2; ++fj) {
                    accz[fi][fj]  = __builtin_amdgcn_mfma_f32_16x16x32_bf16(af[fi], bz[fj],  accz[fi][fj],  0, 0, 0);
                    accza[fi][fj] = __builtin_amdgcn_mfma_f32_16x16x32_bf16(af[fi], bza[fj], accza[fi][fj], 0, 0, 0);
                }
            __syncthreads();
            cur ^= 1;
        }
#undef Z_LOAD
#undef Z_WRITE

        const bool first = (rblk & 15) == 0;       // rows l in [0,64): contains l<=h and diag
        const int b8 = (rblk >> 4) * 8;
#pragma unroll
        for (int fj = 0; fj < 2; ++fj) {
            float lsum = 0.f;
            int lc = wn * 32 + fj * 16 + (lane & 15);
            int col = col0 + lc;
            float Bz = b_z[col], Bza = b_za[col];
#pragma unroll
            for (int fi = 0; fi < 2; ++fi) {
#pragma unroll
                for (int q = 0; q < 4; ++q) {
                    int lr = wm * 32 + fi * 16 + ((lane >> 4) << 2) + q;
                    float pz = accz[fi][fj][q] + Bz;
                    float pza = accza[fi][fj][q] + Bza;
                    float v = pz * siluf_(pza);
                    if (!first || lr > bx) lsum += v;
                    if (first && lr == bx) zdiag[(b8 + bx) * 64 + lc] = v;
                }
            }
            red[lc][wm * 4 + (lane >> 4)] = lsum;
        }
        __syncthreads();
        if (tid < 64) {
            float s = 0.f;
#pragma unroll
            for (int j = 0; j < 8; ++j) s += red[tid][j];
            Zs_part[((size_t)rblk * 8 + bx) * 64 + tid] = s;   // race-free partials
        }
    } else {
        // ================= ya family (gate) =================
        const unsigned short* gWya = Wya + (size_t)(col0 + sr_) * 512 + sc_ * 8;
        f32x4 accya[2][2];
#pragma unroll
        for (int a = 0; a < 2; ++a)
#pragma unroll
            for (int bq = 0; bq < 2; ++bq) accya[a][bq] = zf;

        int4 rxa, rya;
#define Y_LOAD(K) { rxa = *(const int4*)(gXa + (K)); rya = *(const int4*)(gWya + (K)); }
#define Y_WRITE(BUF) { *(int4*)((char*)As[BUF] + sld) = rxa; \
                       *(int4*)((char*)Bs[BUF][0] + sld) = rya; }

        Y_LOAD(0);
        Y_WRITE(0);
        Y_LOAD(32);
        __syncthreads();

        int cur = 0;
        for (int s = 0; s < 16; ++s) {
            if (s < 15) {
                Y_WRITE(cur ^ 1);
                if (s < 14) Y_LOAD((s + 2) * 32);
            }
            short8 af[2], bya[2];
#pragma unroll
            for (int fi = 0; fi < 2; ++fi) {
                int rr = wm * 32 + fi * 16 + (lane & 15);
                af[fi] = *(const short8*)((const char*)As[cur] + rr * RS + ck);
            }
#pragma unroll
            for (int fj = 0; fj < 2; ++fj) {
                int rr = wn * 32 + fj * 16 + (lane & 15);
                bya[fj] = *(const short8*)((const char*)Bs[cur][0] + rr * RS + ck);
            }
#pragma unroll
            for (int fi = 0; fi < 2; ++fi)
#pragma unroll
                for (int fj = 0; fj < 2; ++fj)
                    accya[fi][fj] = __builtin_amdgcn_mfma_f32_16x16x32_bf16(af[fi], bya[fj], accya[fi][fj], 0, 0, 0);
            __syncthreads();
            cur ^= 1;
        }
#undef Y_LOAD
#undef Y_WRITE

#pragma unroll
        for (int fj = 0; fj < 2; ++fj) {
            int lc = wn * 32 + fj * 16 + (lane & 15);
            int col = col0 + lc;
            float Bya = b_ya[col];
#pragma unroll
            for (int fi = 0; fi < 2; ++fi)
#pragma unroll
                for (int q = 0; q < 4; ++q) {
                    int lr = wm * 32 + fi * 16 + ((lane >> 4) << 2) + q;
                    int row = row0 + lr;
                    gateb[(size_t)row * 512 + col] = f2bf(siluf_(accya[fi][fj][q] + Bya));
                }
        }
    }
}

// ========== K3: 32-row blocks (3 blocks/CU): inline hgn -> LDS bf16 + reg-pipelined gemm_y ====
// grid = 512: cbx = bid&7 (same-Wy-panel per XCD), rsub = bid>>3 (0..63), row0 = rsub*32.
__global__ __launch_bounds__(256) void k3_hgn_gemm_y(
    const unsigned short* __restrict__ Wy, const float* __restrict__ b_y,
    const unsigned short* __restrict__ gateb,
    const float* __restrict__ Sr, const float* __restrict__ Si,
    const float* __restrict__ Zs_part, const float* __restrict__ zdiag,
    const float* __restrict__ lc_r, const float* __restrict__ lc_i,
    const float* __restrict__ gn_w, const float* __restrict__ gn_b,
    float* __restrict__ y)
{
    __shared__ unsigned short hA[32][520];          // 1040B row stride (period-8 slot cycle)
    __shared__ short Bs[2][64 * RSS];
    __shared__ float Cr[8][65], Ci[8][65], Zd[8][65];
    const int tid = threadIdx.x;
    const int lane = tid & 63, w = tid >> 6;
    const int cbx = blockIdx.x & 7;
    const int rsub = blockIdx.x >> 3;               // 0..63
    const int row0 = rsub * 32, col0 = cbx * 64;
    const int b = row0 >> 10;                       // L_=1024

    // ---- prologue: issue Wy tiles 0 and 1 into regs; latency hides under hgn phase ----
    const int brow = tid >> 2, bsc = tid & 3;       // 64 rows x 4 chunks of 16B
    const size_t gB = (size_t)(col0 + brow) * 512 + bsc * 8;
    const int bwr = brow * RS + bsc * 16;
    int4 rw0 = *(const int4*)(Wy + gB);
    int4 rw1 = *(const int4*)(Wy + gB + 32);

    // ---- stage per-(h,i) constants: Zs (reduced from partials) + lc, zdiag ----
    for (int uu = tid; uu < 512; uu += 256) {
        int h = uu >> 6, i = uu & 63;
        float s = 0.f;
#pragma unroll
        for (int rb = 0; rb < 16; ++rb)
            s += Zs_part[(((size_t)b * 16 + rb) * 8 + h) * 64 + i];
        Cr[h][i] = s + lc_r[h * 64 + i];
        Ci[h][i] = lc_i[h * 64 + i];
        Zd[h][i] = zdiag[((size_t)b * 8 + h) * 64 + i];
    }
    __syncthreads();

    // ---- phase 1: h + GroupNorm, one (row, head) per thread, write bf16 into hA ----
    {
        const int r = tid >> 3, h = tid & 7;        // r in 0..31
        const int row = row0 + r;
        const float sr = Sr[(size_t)row * 8 + h];
        const float si = Si[(size_t)row * 8 + h];
        const float er = expf(sr);
        const float ca = er * cosf(si), sb = er * sinf(si);
        float sum = 0.f, sq = 0.f;
#pragma unroll 8
        for (int i = 0; i < 64; ++i) {
            float hv = Zd[h][i] + ca * Cr[h][i] - sb * Ci[h][i];
            sum += hv; sq += hv * hv;
        }
        const float mean = sum * (1.f / 64.f);
        const float inv = rsqrtf(sq * (1.f / 64.f) - mean * mean + 1e-5f);
        const float gw = gn_w[h] * inv;
        const float gb = gn_b[h] - mean * gw;
#pragma unroll
        for (int s8 = 0; s8 < 8; ++s8) {
            short8 pk;
#pragma unroll
            for (int j = 0; j < 8; ++j) {
                int i = s8 * 8 + j;
                float hv = Zd[h][i] + ca * Cr[h][i] - sb * Ci[h][i];
                pk[j] = (short)f2bf(hv * gw + gb);
            }
            int slot = (s8 + h) & 7;   // per-head slot rotation: conflict-free writes
            *(short8*)((char*)&hA[r][0] + h * 128 + slot * 16) = pk;
        }
    }
    *(int4*)((char*)Bs[0] + bwr) = rw0;             // stage Wy tile 0
    __syncthreads();

    // ---- phase 2: y = (hA @ Wy^T(bf16) + b_y) * gate, reg-pipelined Wy, 4 col-quarter waves --
    const f32x4 zf = {0.f, 0.f, 0.f, 0.f};
    f32x4 acc[2] = {zf, zf};

    int cur = 0;
    for (int s = 0; s < 16; ++s) {
        if (s < 15) {
            *(int4*)((char*)Bs[cur ^ 1] + bwr) = rw1;               // stage tile s+1
            if (s < 14) rw1 = *(const int4*)(Wy + gB + (s + 2) * 32);   // prefetch s+2
        }
        const int k0 = s * 32;
        short8 af[2], bf;
        const int hk = k0 >> 6;
        const int t = ((k0 & 32) >> 3) + (lane >> 4);
        const int slot = (t + hk) & 7;              // undo phase-1 rotation
#pragma unroll
        for (int fi = 0; fi < 2; ++fi) {
            int rr = fi * 16 + (lane & 15);
            af[fi] = *(const short8*)((const char*)&hA[rr][0] + hk * 128 + slot * 16);
        }
        {
            int rr = w * 16 + (lane & 15);
            bf = *(const short8*)((const char*)Bs[cur] + rr * RS + ((lane >> 4) << 4));
        }
        acc[0] = __builtin_amdgcn_mfma_f32_16x16x32_bf16(af[0], bf, acc[0], 0, 0, 0);
        acc[1] = __builtin_amdgcn_mfma_f32_16x16x32_bf16(af[1], bf, acc[1], 0, 0, 0);
        __syncthreads();
        cur ^= 1;
    }

    const int col = col0 + w * 16 + (lane & 15);
    const float By = b_y[col];
#pragma unroll
    for (int fi = 0; fi < 2; ++fi)
#pragma unroll
        for (int q = 0; q < 4; ++q) {
            int row = row0 + fi * 16 + ((lane >> 4) << 2) + q;
            size_t idx = (size_t)row * 512 + col;
            y[idx] = (acc[fi][q] + By) * bf2f(gateb[idx]);
        }
}

extern "C" void kernel_launch(void* const* d_in, const int* in_sizes, int n_in,
                              void* d_out, int out_size, void* d_ws, size_t ws_size,
                              hipStream_t stream) {
    (void)n_in; (void)out_size; (void)ws_size;
    const float* x     = (const float*)d_in[0];
    const float* w_z   = (const float*)d_in[1];
    const float* b_z   = (const float*)d_in[2];
    const float* w_za  = (const float*)d_in[3];
    const float* b_za  = (const float*)d_in[4];
    const float* w_ang = (const float*)d_in[5];
    const float* b_ang = (const float*)d_in[6];
    const float* w_abs = (const float*)d_in[7];
    const float* b_abs = (const float*)d_in[8];
    const float* w_y   = (const float*)d_in[9];
    const float* b_y   = (const float*)d_in[10];
    const float* w_ya  = (const float*)d_in[11];
    const float* b_ya  = (const float*)d_in[12];
    const float* gn_w  = (const float*)d_in[13];
    const float* gn_b  = (const float*)d_in[14];
    const float* lc_r  = (const float*)d_in[15];
    const float* lc_i  = (const float*)d_in[16];
    float* y = (float*)d_out;

    const int BL = in_sizes[0] / D_;   // 2048
    const int B  = BL / L_;            // 2

    unsigned short* wtz  = (unsigned short*)d_ws;            // 512*512 each
    unsigned short* wtza = wtz  + 512 * 512;
    unsigned short* wtya = wtza + 512 * 512;
    unsigned short* wty  = wtya + 512 * 512;
    unsigned short* gateb= wty  + 512 * 512;                 // BL*512
    unsigned short* xb   = gateb + (size_t)BL * 512;         // BL*512 bf16
    float* a_arr = (float*)(xb + (size_t)BL * 512);          // BL*H
    float* r_arr = a_arr + (size_t)BL * H_;
    float* Si    = r_arr + (size_t)BL * H_;
    float* Sr    = Si    + (size_t)BL * H_;
    float* zdiag = Sr    + (size_t)BL * H_;                  // B*H*I
    float* Zs_part = zdiag + (size_t)B * H_ * I_;            // (BL/64)*H*I

    const int ntiles = (BL / 64) * 8;       // 256

    k1_prep<<<256 + BL / 4, 256, 0, stream>>>(
        x, xb, w_z, w_za, w_ya, w_y, wtz, wtza, wtya, wty,
        w_ang, b_ang, w_abs, b_abs, a_arr, r_arr);
    k2_split<<<16 + 2 * ntiles, 256, 0, stream>>>(
        xb, wtz, wtza, wtya, b_z, b_za, b_ya,
        gateb, Zs_part, zdiag, a_arr, r_arr, Si, Sr);
    k3_hgn_gemm_y<<<2 * ntiles, 256, 0, stream>>>(
        wty, b_y, gateb, Sr, Si, Zs_part, zdiag, lc_r, lc_i, gn_w, gn_b, y);
}

// Round 18
// 39.948 us; speedup vs baseline: 2.3366x; 1.0112x over previous
//
#include <hip/hip_runtime.h>
#include <math.h>

#define D_ 512
#define H_ 8
#define I_ 64
#define L_ 1024

typedef __attribute__((ext_vector_type(8))) short short8;
typedef __attribute__((ext_vector_type(4))) float f32x4;

__device__ __forceinline__ float sigmoidf_(float x) { return 1.f / (1.f + expf(-x)); }
__device__ __forceinline__ float siluf_(float x) { return x / (1.f + expf(-x)); }

__device__ __forceinline__ unsigned short f2bf(float f) {
    unsigned u = __float_as_uint(f);
    u += 0x7fffu + ((u >> 16) & 1u);   // round-to-nearest-even
    return (unsigned short)(u >> 16);
}
__device__ __forceinline__ float bf2f(unsigned short v) {
    return __uint_as_float((unsigned)v << 16);
}

// Staging tiles are [64 rows][32 k] bf16 with 80B row stride (64B rows alias banks
// every 2 rows -> 8-way b128 conflicts, R8/R9: 2.77M cycles; 80B -> 2-way, free).
#define RS 80        // row stride in bytes
#define RSS 40       // row stride in shorts

// ========== K1: 4x W transpose (256 blocks) + angabs heads + xb bf16 (BL/4 blocks) ==========
__global__ __launch_bounds__(256) void k1_prep(
    const float* __restrict__ x, unsigned short* __restrict__ xb,
    const float* __restrict__ w0, const float* __restrict__ w1,
    const float* __restrict__ w2, const float* __restrict__ w3,
    unsigned short* __restrict__ t0, unsigned short* __restrict__ t1,
    unsigned short* __restrict__ t2, unsigned short* __restrict__ t3,
    const float* __restrict__ w_ang, const float* __restrict__ b_ang,
    const float* __restrict__ w_abs, const float* __restrict__ b_abs,
    float* __restrict__ a_out, float* __restrict__ r_out)
{
    __shared__ float sm[64][65];
    const int tid = threadIdx.x;
    const int bid = blockIdx.x;
    if (bid < 256) {
        // ---- W[k][n] -> Wt[n][k] bf16 ----
        int zsel = bid >> 6, tile = bid & 63;
        const float* src = zsel == 0 ? w0 : zsel == 1 ? w1 : zsel == 2 ? w2 : w3;
        unsigned short* dst = zsel == 0 ? t0 : zsel == 1 ? t1 : zsel == 2 ? t2 : t3;
        const int k0 = (tile >> 3) * 64, n0 = (tile & 7) * 64;
#pragma unroll
        for (int i = 0; i < 16; ++i) {
            int idx = tid + i * 256;
            int rr = idx >> 6, cc = idx & 63;
            sm[rr][cc] = src[(size_t)(k0 + rr) * 512 + n0 + cc];
        }
        __syncthreads();
#pragma unroll
        for (int i = 0; i < 16; ++i) {
            int idx = tid + i * 256;
            int rr = idx >> 6, cc = idx & 63;   // rr = n-local, cc = k-local
            dst[(size_t)(n0 + rr) * 512 + k0 + cc] = f2bf(sm[cc][rr]);
        }
        return;
    }
    // ---- angabs + xb: stage 4 rows in LDS, emit bf16 x, compute head dots from LDS ----
    {
        float* xs = &sm[0][0];                 // 2048 floats (fits in sm)
        const int t = bid - 256;
        const int n0 = t * 4;
#pragma unroll
        for (int p = 0; p < 2; ++p) {
            int idx = (p * 256 + tid) * 4;     // 0..2047 floats
            int rr = idx >> 9, cc = idx & 511;
            float4 v = *(const float4*)(x + (size_t)(n0 + rr) * 512 + cc);
            *(float4*)(xs + idx) = v;
            ushort4 o = { f2bf(v.x), f2bf(v.y), f2bf(v.z), f2bf(v.w) };
            *(ushort4*)(xb + (size_t)(n0 + rr) * 512 + cc) = o;
        }
        __syncthreads();
        const int s = tid & 3, c = (tid >> 2) & 15, r = tid >> 6;
        const int h = c & 7;
        const float* wp = (c < 8) ? w_ang : w_abs;
        const float* xr = xs + r * 512;
        float acc = 0.f;
#pragma unroll 4
        for (int i = 0; i < 128; ++i) {
            int k = i * 4 + s;
            acc = fmaf(xr[k], wp[k * H_ + h], acc);
        }
        acc += __shfl_xor(acc, 1);
        acc += __shfl_xor(acc, 2);
        if (s == 0) {
            const int n = n0 + r;
            const float scale = expf(-6.9077552789821368f * (h * (1.0f / 7.0f)));  // 0.001^(h/7)
            if (c < 8) { float p = acc + b_ang[h]; a_out[(size_t)n * H_ + h] = siluf_(p) * scale; }
            else       { float p = acc + b_abs[h]; r_out[(size_t)n * H_ + h] = sigmoidf_(p) * scale; }
        }
    }
}

// ===== K2: split GEMM families; DEPTH-4 register prefetch pipeline (latency coverage) =====
// Slot schedule (fixed R17 off-by-one): prologue loads tiles 0-3 into slots 0-3,
// stages slot0->buf0, then RELOADS slot0 <- tile4. Step SIDX: compute buf[SIDX&1];
// write slot (SIDX+1)&3 (holds tile SIDX+1) -> buf[(SIDX+1)&1]; reload it <- tile SIDX+5.
// Slot coverage: s0:{t4,t8,t12} s1:{t1,t5,t9,t13} s2:{t2,t6,t10,t14} s3:{t3,t7,t11,t15}.
__global__ __launch_bounds__(256) void k2_split(
    const unsigned short* __restrict__ xb,
    const unsigned short* __restrict__ Wz, const unsigned short* __restrict__ Wza,
    const unsigned short* __restrict__ Wya,
    const float* __restrict__ b_z, const float* __restrict__ b_za, const float* __restrict__ b_ya,
    unsigned short* __restrict__ gateb, float* __restrict__ Zs_part, float* __restrict__ zdiag,
    const float* __restrict__ a_arr, const float* __restrict__ r_arr,
    float* __restrict__ Si, float* __restrict__ Sr)
{
    __shared__ short As[2][64 * RSS];
    __shared__ short Bs[2][2][64 * RSS];
    __shared__ float red[64][8];
    __shared__ float2 buf[2][256];
    const int tid = threadIdx.x;
    const int bid = blockIdx.x;

    if (bid < 16) {
        // ---------- scan rider: inclusive cumsum over l for one (b,h) ----------
        const int b = bid >> 3, h = bid & 7;
        float2 v[4];
        float2 run = make_float2(0.f, 0.f);
        const size_t base = ((size_t)b * L_ + tid * 4) * H_ + h;
#pragma unroll
        for (int j = 0; j < 4; ++j) {
            run.x += a_arr[base + j * H_];
            run.y += r_arr[base + j * H_];
            v[j] = run;
        }
        buf[0][tid] = run;
        __syncthreads();
        int src = 0;
        for (int off = 1; off < 256; off <<= 1) {
            float2 val = buf[src][tid];
            if (tid >= off) { float2 q = buf[src][tid - off]; val.x += q.x; val.y += q.y; }
            buf[src ^ 1][tid] = val;
            src ^= 1;
            __syncthreads();
        }
        float2 excl = make_float2(0.f, 0.f);
        if (tid > 0) excl = buf[src][tid - 1];
#pragma unroll
        for (int j = 0; j < 4; ++j) {
            Si[base + j * H_] = v[j].x + excl.x;
            Sr[base + j * H_] = -(v[j].y + excl.y);
        }
        return;
    }

    const bool zza = bid < 272;
    const int u = zza ? (bid - 16) : (bid - 272);   // 0..255 (both offsets %8 == 0)
    const int rblk = (u & 7) * 4 + (u >> 6);        // same rblk -> same bid%8 -> same XCD
    const int bx = (u >> 3) & 7;                    // col panel == head
    const int lane = tid & 63, w = tid >> 6;
    const int wm = w >> 1, wn = w & 1;
    const int row0 = rblk * 64, col0 = bx * 64;

    const f32x4 zf = {0.f, 0.f, 0.f, 0.f};
    const int sr_ = tid >> 2, sc_ = tid & 3;
    const int sld = sr_ * RS + sc_ * 16;            // padded-stride LDS byte offset
    const unsigned short* gXa = xb + (size_t)(row0 + sr_) * 512 + sc_ * 8;
    const int ck = (lane >> 4) << 4;                // 16B chunk within row

    if (zza) {
        // ================= z/za family =================
        const unsigned short* gWz  = Wz  + (size_t)(col0 + sr_) * 512 + sc_ * 8;
        const unsigned short* gWza = Wza + (size_t)(col0 + sr_) * 512 + sc_ * 8;
        f32x4 accz[2][2], accza[2][2];
#pragma unroll
        for (int a = 0; a < 2; ++a)
#pragma unroll
            for (int bq = 0; bq < 2; ++bq) { accz[a][bq] = zf; accza[a][bq] = zf; }

        auto z_compute = [&](int CB) {
            short8 af[2], bz[2], bza[2];
#pragma unroll
            for (int fi = 0; fi < 2; ++fi) {
                int rr = wm * 32 + fi * 16 + (lane & 15);
                af[fi] = *(const short8*)((const char*)As[CB] + rr * RS + ck);
            }
#pragma unroll
            for (int fj = 0; fj < 2; ++fj) {
                int rr = wn * 32 + fj * 16 + (lane & 15);
                bz[fj]  = *(const short8*)((const char*)Bs[CB][0] + rr * RS + ck);
                bza[fj] = *(const short8*)((const char*)Bs[CB][1] + rr * RS + ck);
            }
#pragma unroll
            for (int fi = 0; fi < 2; ++fi)
#pragma unroll
                for (int fj = 0; fj < 2; ++fj) {
                    accz[fi][fj]  = __builtin_amdgcn_mfma_f32_16x16x32_bf16(af[fi], bz[fj],  accz[fi][fj],  0, 0, 0);
                    accza[fi][fj] = __builtin_amdgcn_mfma_f32_16x16x32_bf16(af[fi], bza[fj], accza[fi][fj], 0, 0, 0);
                }
        };

        int4 rxa0, rz0, rza0, rxa1, rz1, rza1, rxa2, rz2, rza2, rxa3, rz3, rza3;
#define Z_LOAD(S, K) { rxa##S = *(const int4*)(gXa + (K)); \
                       rz##S  = *(const int4*)(gWz  + (K)); \
                       rza##S = *(const int4*)(gWza + (K)); }
#define Z_WRITE(S, BUF) { *(int4*)((char*)As[BUF] + sld) = rxa##S; \
                          *(int4*)((char*)Bs[BUF][0] + sld) = rz##S; \
                          *(int4*)((char*)Bs[BUF][1] + sld) = rza##S; }
#define Z_STEP(CB, WS, WB, SIDX) { \
            z_compute(CB); \
            if ((SIDX) < 15) { \
                Z_WRITE(WS, WB) \
                if ((SIDX) <= 10) Z_LOAD(WS, ((SIDX) + 5) * 32) \
            } \
            __syncthreads(); }

        Z_LOAD(0, 0) Z_LOAD(1, 32) Z_LOAD(2, 64) Z_LOAD(3, 96)
        Z_WRITE(0, 0)
        Z_LOAD(0, 128)                         // slot0 <- tile4 (fixes R17 off-by-one)
        __syncthreads();

        for (int g = 0; g < 4; ++g) {
            const int s0 = g * 4;
            Z_STEP(0, 1, 1, s0)
            Z_STEP(1, 2, 0, s0 + 1)
            Z_STEP(0, 3, 1, s0 + 2)
            Z_STEP(1, 0, 0, s0 + 3)
        }
#undef Z_LOAD
#undef Z_WRITE
#undef Z_STEP

        const bool first = (rblk & 15) == 0;       // rows l in [0,64): contains l<=h and diag
        const int b8 = (rblk >> 4) * 8;
#pragma unroll
        for (int fj = 0; fj < 2; ++fj) {
            float lsum = 0.f;
            int lc = wn * 32 + fj * 16 + (lane & 15);
            int col = col0 + lc;
            float Bz = b_z[col], Bza = b_za[col];
#pragma unroll
            for (int fi = 0; fi < 2; ++fi) {
#pragma unroll
                for (int q = 0; q < 4; ++q) {
                    int lr = wm * 32 + fi * 16 + ((lane >> 4) << 2) + q;
                    float pz = accz[fi][fj][q] + Bz;
                    float pza = accza[fi][fj][q] + Bza;
                    float v = pz * siluf_(pza);
                    if (!first || lr > bx) lsum += v;
                    if (first && lr == bx) zdiag[(b8 + bx) * 64 + lc] = v;
                }
            }
            red[lc][wm * 4 + (lane >> 4)] = lsum;
        }
        __syncthreads();
        if (tid < 64) {
            float s = 0.f;
#pragma unroll
            for (int j = 0; j < 8; ++j) s += red[tid][j];
            Zs_part[((size_t)rblk * 8 + bx) * 64 + tid] = s;   // race-free partials
        }
    } else {
        // ================= ya family (gate) =================
        const unsigned short* gWya = Wya + (size_t)(col0 + sr_) * 512 + sc_ * 8;
        f32x4 accya[2][2];
#pragma unroll
        for (int a = 0; a < 2; ++a)
#pragma unroll
            for (int bq = 0; bq < 2; ++bq) accya[a][bq] = zf;

        auto y_compute = [&](int CB) {
            short8 af[2], bya[2];
#pragma unroll
            for (int fi = 0; fi < 2; ++fi) {
                int rr = wm * 32 + fi * 16 + (lane & 15);
                af[fi] = *(const short8*)((const char*)As[CB] + rr * RS + ck);
            }
#pragma unroll
            for (int fj = 0; fj < 2; ++fj) {
                int rr = wn * 32 + fj * 16 + (lane & 15);
                bya[fj] = *(const short8*)((const char*)Bs[CB][0] + rr * RS + ck);
            }
#pragma unroll
            for (int fi = 0; fi < 2; ++fi)
#pragma unroll
                for (int fj = 0; fj < 2; ++fj)
                    accya[fi][fj] = __builtin_amdgcn_mfma_f32_16x16x32_bf16(af[fi], bya[fj], accya[fi][fj], 0, 0, 0);
        };

        int4 rxa0, rya0, rxa1, rya1, rxa2, rya2, rxa3, rya3;
#define Y_LOAD(S, K) { rxa##S = *(const int4*)(gXa + (K)); \
                       rya##S = *(const int4*)(gWya + (K)); }
#define Y_WRITE(S, BUF) { *(int4*)((char*)As[BUF] + sld) = rxa##S; \
                          *(int4*)((char*)Bs[BUF][0] + sld) = rya##S; }
#define Y_STEP(CB, WS, WB, SIDX) { \
            y_compute(CB); \
            if ((SIDX) < 15) { \
                Y_WRITE(WS, WB) \
                if ((SIDX) <= 10) Y_LOAD(WS, ((SIDX) + 5) * 32) \
            } \
            __syncthreads(); }

        Y_LOAD(0, 0) Y_LOAD(1, 32) Y_LOAD(2, 64) Y_LOAD(3, 96)
        Y_WRITE(0, 0)
        Y_LOAD(0, 128)                         // slot0 <- tile4 (fixes R17 off-by-one)
        __syncthreads();

        for (int g = 0; g < 4; ++g) {
            const int s0 = g * 4;
            Y_STEP(0, 1, 1, s0)
            Y_STEP(1, 2, 0, s0 + 1)
            Y_STEP(0, 3, 1, s0 + 2)
            Y_STEP(1, 0, 0, s0 + 3)
        }
#undef Y_LOAD
#undef Y_WRITE
#undef Y_STEP

#pragma unroll
        for (int fj = 0; fj < 2; ++fj) {
            int lc = wn * 32 + fj * 16 + (lane & 15);
            int col = col0 + lc;
            float Bya = b_ya[col];
#pragma unroll
            for (int fi = 0; fi < 2; ++fi)
#pragma unroll
                for (int q = 0; q < 4; ++q) {
                    int lr = wm * 32 + fi * 16 + ((lane >> 4) << 2) + q;
                    int row = row0 + lr;
                    gateb[(size_t)row * 512 + col] = f2bf(siluf_(accya[fi][fj][q] + Bya));
                }
        }
    }
}

// ========== K3: 32-row blocks: inline hgn -> LDS bf16 + DEPTH-4 prefetched gemm_y ==========
// grid = 512: cbx = bid&7 (same-Wy-panel per XCD), rsub = bid>>3 (0..63), row0 = rsub*32.
__global__ __launch_bounds__(256) void k3_hgn_gemm_y(
    const unsigned short* __restrict__ Wy, const float* __restrict__ b_y,
    const unsigned short* __restrict__ gateb,
    const float* __restrict__ Sr, const float* __restrict__ Si,
    const float* __restrict__ Zs_part, const float* __restrict__ zdiag,
    const float* __restrict__ lc_r, const float* __restrict__ lc_i,
    const float* __restrict__ gn_w, const float* __restrict__ gn_b,
    float* __restrict__ y)
{
    __shared__ unsigned short hA[32][520];          // 1040B row stride (period-8 slot cycle)
    __shared__ short Bs[2][64 * RSS];
    __shared__ float Cr[8][65], Ci[8][65], Zd[8][65];
    const int tid = threadIdx.x;
    const int lane = tid & 63, w = tid >> 6;
    const int cbx = blockIdx.x & 7;
    const int rsub = blockIdx.x >> 3;               // 0..63
    const int row0 = rsub * 32, col0 = cbx * 64;
    const int b = row0 >> 10;                       // L_=1024

    // ---- prologue: issue Wy tiles 0..3 into regs; latency hides under hgn phase ----
    const int brow = tid >> 2, bsc = tid & 3;       // 64 rows x 4 chunks of 16B
    const size_t gB = (size_t)(col0 + brow) * 512 + bsc * 8;
    const int bwr = brow * RS + bsc * 16;
    int4 rw0 = *(const int4*)(Wy + gB);
    int4 rw1 = *(const int4*)(Wy + gB + 32);
    int4 rw2 = *(const int4*)(Wy + gB + 64);
    int4 rw3 = *(const int4*)(Wy + gB + 96);

    // ---- stage per-(h,i) constants: Zs (reduced from partials) + lc, zdiag ----
    for (int uu = tid; uu < 512; uu += 256) {
        int h = uu >> 6, i = uu & 63;
        float s = 0.f;
#pragma unroll
        for (int rb = 0; rb < 16; ++rb)
            s += Zs_part[(((size_t)b * 16 + rb) * 8 + h) * 64 + i];
        Cr[h][i] = s + lc_r[h * 64 + i];
        Ci[h][i] = lc_i[h * 64 + i];
        Zd[h][i] = zdiag[((size_t)b * 8 + h) * 64 + i];
    }
    __syncthreads();

    // ---- phase 1: h + GroupNorm, one (row, head) per thread, write bf16 into hA ----
    {
        const int r = tid >> 3, h = tid & 7;        // r in 0..31
        const int row = row0 + r;
        const float sr = Sr[(size_t)row * 8 + h];
        const float si = Si[(size_t)row * 8 + h];
        const float er = expf(sr);
        const float ca = er * cosf(si), sb = er * sinf(si);
        float sum = 0.f, sq = 0.f;
#pragma unroll 8
        for (int i = 0; i < 64; ++i) {
            float hv = Zd[h][i] + ca * Cr[h][i] - sb * Ci[h][i];
            sum += hv; sq += hv * hv;
        }
        const float mean = sum * (1.f / 64.f);
        const float inv = rsqrtf(sq * (1.f / 64.f) - mean * mean + 1e-5f);
        const float gw = gn_w[h] * inv;
        const float gb = gn_b[h] - mean * gw;
#pragma unroll
        for (int s8 = 0; s8 < 8; ++s8) {
            short8 pk;
#pragma unroll
            for (int j = 0; j < 8; ++j) {
                int i = s8 * 8 + j;
                float hv = Zd[h][i] + ca * Cr[h][i] - sb * Ci[h][i];
                pk[j] = (short)f2bf(hv * gw + gb);
            }
            int slot = (s8 + h) & 7;   // per-head slot rotation: conflict-free writes
            *(short8*)((char*)&hA[r][0] + h * 128 + slot * 16) = pk;
        }
    }
    *(int4*)((char*)Bs[0] + bwr) = rw0;             // stage Wy tile 0
    rw0 = *(const int4*)(Wy + gB + 128);            // rw0 <- tile4 (fixes R17 off-by-one)
    __syncthreads();

    // ---- phase 2: y = (hA @ Wy^T + b_y) * gate, depth-4 prefetched Wy ----
    const f32x4 zf = {0.f, 0.f, 0.f, 0.f};
    f32x4 acc[2] = {zf, zf};

    auto k3_compute = [&](int CB, int s) {
        const int k0 = s * 32;
        short8 af[2], bf;
        const int hk = k0 >> 6;
        const int t = ((k0 & 32) >> 3) + (lane >> 4);
        const int slot = (t + hk) & 7;              // undo phase-1 rotation
#pragma unroll
        for (int fi = 0; fi < 2; ++fi) {
            int rr = fi * 16 + (lane & 15);
            af[fi] = *(const short8*)((const char*)&hA[rr][0] + hk * 128 + slot * 16);
        }
        {
            int rr = w * 16 + (lane & 15);
            bf = *(const short8*)((const char*)Bs[CB] + rr * RS + ((lane >> 4) << 4));
        }
        acc[0] = __builtin_amdgcn_mfma_f32_16x16x32_bf16(af[0], bf, acc[0], 0, 0, 0);
        acc[1] = __builtin_amdgcn_mfma_f32_16x16x32_bf16(af[1], bf, acc[1], 0, 0, 0);
    };

#define K3_STEP(CB, WS, WB, SIDX) { \
        k3_compute(CB, SIDX); \
        if ((SIDX) < 15) { \
            *(int4*)((char*)Bs[WB] + bwr) = rw##WS; \
            if ((SIDX) <= 10) rw##WS = *(const int4*)(Wy + gB + ((SIDX) + 5) * 32); \
        } \
        __syncthreads(); }

    for (int g = 0; g < 4; ++g) {
        const int s0 = g * 4;
        K3_STEP(0, 1, 1, s0)
        K3_STEP(1, 2, 0, s0 + 1)
        K3_STEP(0, 3, 1, s0 + 2)
        K3_STEP(1, 0, 0, s0 + 3)
    }
#undef K3_STEP

    const int col = col0 + w * 16 + (lane & 15);
    const float By = b_y[col];
#pragma unroll
    for (int fi = 0; fi < 2; ++fi)
#pragma unroll
        for (int q = 0; q < 4; ++q) {
            int row = row0 + fi * 16 + ((lane >> 4) << 2) + q;
            size_t idx = (size_t)row * 512 + col;
            y[idx] = (acc[fi][q] + By) * bf2f(gateb[idx]);
        }
}

extern "C" void kernel_launch(void* const* d_in, const int* in_sizes, int n_in,
                              void* d_out, int out_size, void* d_ws, size_t ws_size,
                              hipStream_t stream) {
    (void)n_in; (void)out_size; (void)ws_size;
    const float* x     = (const float*)d_in[0];
    const float* w_z   = (const float*)d_in[1];
    const float* b_z   = (const float*)d_in[2];
    const float* w_za  = (const float*)d_in[3];
    const float* b_za  = (const float*)d_in[4];
    const float* w_ang = (const float*)d_in[5];
    const float* b_ang = (const float*)d_in[6];
    const float* w_abs = (const float*)d_in[7];
    const float* b_abs = (const float*)d_in[8];
    const float* w_y   = (const float*)d_in[9];
    const float* b_y   = (const float*)d_in[10];
    const float* w_ya  = (const float*)d_in[11];
    const float* b_ya  = (const float*)d_in[12];
    const float* gn_w  = (const float*)d_in[13];
    const float* gn_b  = (const float*)d_in[14];
    const float* lc_r  = (const float*)d_in[15];
    const float* lc_i  = (const float*)d_in[16];
    float* y = (float*)d_out;

    const int BL = in_sizes[0] / D_;   // 2048
    const int B  = BL / L_;            // 2

    unsigned short* wtz  = (unsigned short*)d_ws;            // 512*512 each
    unsigned short* wtza = wtz  + 512 * 512;
    unsigned short* wtya = wtza + 512 * 512;
    unsigned short* wty  = wtya + 512 * 512;
    unsigned short* gateb= wty  + 512 * 512;                 // BL*512
    unsigned short* xb   = gateb + (size_t)BL * 512;         // BL*512 bf16
    float* a_arr = (float*)(xb + (size_t)BL * 512);          // BL*H
    float* r_arr = a_arr + (size_t)BL * H_;
    float* Si    = r_arr + (size_t)BL * H_;
    float* Sr    = Si    + (size_t)BL * H_;
    float* zdiag = Sr    + (size_t)BL * H_;                  // B*H*I
    float* Zs_part = zdiag + (size_t)B * H_ * I_;            // (BL/64)*H*I

    const int ntiles = (BL / 64) * 8;       // 256

    k1_prep<<<256 + BL / 4, 256, 0, stream>>>(
        x, xb, w_z, w_za, w_ya, w_y, wtz, wtza, wtya, wty,
        w_ang, b_ang, w_abs, b_abs, a_arr, r_arr);
    k2_split<<<16 + 2 * ntiles, 256, 0, stream>>>(
        xb, wtz, wtza, wtya, b_z, b_za, b_ya,
        gateb, Zs_part, zdiag, a_arr, r_arr, Si, Sr);
    k3_hgn_gemm_y<<<2 * ntiles, 256, 0, stream>>>(
        wty, b_y, gateb, Sr, Si, Zs_part, zdiag, lc_r, lc_i, gn_w, gn_b, y);
}